// Round 4
// baseline (987.618 us; speedup 1.0000x reference)
//
#include <hip/hip_runtime.h>
#include <math.h>

#define NN 20000
#define HID 128
#define NH 8
#define HD 16
#define LAPD 16
#define NB 1024
#define NBINS 32
#define MAXDEG 64
#define NE 320000
#define DIN 144

// finite "minus infinity" sentinel: never produces inf/NaN arithmetic,
// exp(x - NEGH) underflows to 0 in hardware. Real scores are |s| < ~1e4.
#define NEGH (-1.0e30f)

// ---------------- MLP: l = relu([X,lap]@W1+b1)@W2+b2, argmax over 1024 (fp32) ---
__global__ __launch_bounds__(256) void mlp_kernel(
    const float* __restrict__ X, const float* __restrict__ lap,
    const float* __restrict__ W1, const float* __restrict__ b1,
    const float* __restrict__ W2, const float* __restrict__ b2,
    float* __restrict__ outL, int* __restrict__ bidx)
{
    __shared__ __align__(16) float xs[16][DIN];
    __shared__ __align__(16) float hs[16][HID];
    __shared__ float rbv[64];
    __shared__ int   rbi[64];
    const int tid = threadIdx.x;
    const int n0 = blockIdx.x * 16;

    for (int e = tid; e < 16 * DIN; e += 256) {
        int n = e / DIN, k = e - n * DIN;
        float v = (k < HID) ? X[(size_t)(n0 + n) * HID + k]
                            : lap[(size_t)(n0 + n) * LAPD + (k - HID)];
        xs[n][k] = v;
    }
    __syncthreads();

    const int c = tid & 127, ng = tid >> 7;
    float hacc[8];
    {
        float bb = b1[c];
        #pragma unroll
        for (int m = 0; m < 8; m++) hacc[m] = bb;
        for (int k = 0; k < DIN; k += 4) {
            float w0 = W1[(k + 0) * HID + c];
            float w1 = W1[(k + 1) * HID + c];
            float w2 = W1[(k + 2) * HID + c];
            float w3 = W1[(k + 3) * HID + c];
            #pragma unroll
            for (int m = 0; m < 8; m++) {
                float4 xv = *(const float4*)&xs[ng * 8 + m][k];
                hacc[m] = fmaf(xv.x, w0, hacc[m]);
                hacc[m] = fmaf(xv.y, w1, hacc[m]);
                hacc[m] = fmaf(xv.z, w2, hacc[m]);
                hacc[m] = fmaf(xv.w, w3, hacc[m]);
            }
        }
    }
    #pragma unroll
    for (int m = 0; m < 8; m++) hs[ng * 8 + m][c] = fmaxf(hacc[m], 0.0f);
    __syncthreads();

    float acc[4][16];
    #pragma unroll
    for (int c4 = 0; c4 < 4; c4++)
        #pragma unroll
        for (int m = 0; m < 16; m++) acc[c4][m] = 0.0f;

    for (int k = 0; k < HID; k += 4) {
        float w[4][4];
        #pragma unroll
        for (int kk = 0; kk < 4; kk++)
            #pragma unroll
            for (int c4 = 0; c4 < 4; c4++)
                w[kk][c4] = W2[(size_t)(k + kk) * NB + c4 * 256 + tid];
        #pragma unroll
        for (int m = 0; m < 16; m++) {
            float4 hv = *(const float4*)&hs[m][k];
            #pragma unroll
            for (int c4 = 0; c4 < 4; c4++) {
                acc[c4][m] = fmaf(hv.x, w[0][c4], acc[c4][m]);
                acc[c4][m] = fmaf(hv.y, w[1][c4], acc[c4][m]);
                acc[c4][m] = fmaf(hv.z, w[2][c4], acc[c4][m]);
                acc[c4][m] = fmaf(hv.w, w[3][c4], acc[c4][m]);
            }
        }
    }

    float bb4[4];
    #pragma unroll
    for (int c4 = 0; c4 < 4; c4++) bb4[c4] = b2[c4 * 256 + tid];

    const int lane = tid & 63, wv = tid >> 6;
    for (int m = 0; m < 16; m++) {
        float bv = -3.0e38f; int bi = 0x7fffffff;
        #pragma unroll
        for (int c4 = 0; c4 < 4; c4++) {
            int o = c4 * 256 + tid;
            float v = acc[c4][m] + bb4[c4];
            outL[(size_t)(n0 + m) * NB + o] = v;
            if (v > bv || (v == bv && o < bi)) { bv = v; bi = o; }
        }
        #pragma unroll
        for (int off = 1; off < 64; off <<= 1) {
            float ov = __shfl_xor(bv, off, 64);
            int   oi = __shfl_xor(bi, off, 64);
            if (ov > bv || (ov == bv && oi < bi)) { bv = ov; bi = oi; }
        }
        if (lane == 0) { rbv[wv * 16 + m] = bv; rbi[wv * 16 + m] = bi; }
    }
    __syncthreads();
    if (tid < 16) {
        float bv = rbv[tid]; int bi = rbi[tid];
        #pragma unroll
        for (int ww = 1; ww < 4; ww++) {
            float ov = rbv[ww * 16 + tid]; int oi = rbi[ww * 16 + tid];
            if (ov > bv || (ov == bv && oi < bi)) { bv = ov; bi = oi; }
        }
        bidx[n0 + tid] = min(max(bi, 0), NB - 1);
    }
}

// ---------------- small utility kernels ----------------------------------------
__global__ void zero_kernel(int* __restrict__ p, int n) {
    int i = blockIdx.x * 256 + threadIdx.x;
    if (i < n) p[i] = 0;
}

__global__ void hist_kernel(const int* __restrict__ bkarr, int* __restrict__ bcnt) {
    int i = blockIdx.x * 256 + threadIdx.x;
    if (i < NN) {
        int b = min(max(bkarr[i], 0), NB - 1);
        atomicAdd(&bcnt[b], 1);
    }
}

__global__ __launch_bounds__(1024) void scan_bucket_kernel(const int* __restrict__ cnt,
        int* __restrict__ off, int* __restrict__ fill) {
    __shared__ int s[1024];
    int t = threadIdx.x;
    int v = cnt[t];
    s[t] = v; __syncthreads();
    for (int o = 1; o < 1024; o <<= 1) {
        int a = (t >= o) ? s[t - o] : 0;
        __syncthreads();
        s[t] += a;
        __syncthreads();
    }
    int excl = s[t] - v;
    off[t] = excl; fill[t] = excl;
    if (t == 1023) off[NB] = s[1023];
}

__global__ __launch_bounds__(1024) void scan_edge_kernel(const int* __restrict__ cnt,
        int* __restrict__ off, int* __restrict__ fill) {
    __shared__ int s[1024];
    const int t = threadIdx.x;
    const int base = t * 20;   // 1024*20 >= 20000
    int loc[20]; int sum = 0;
    #pragma unroll
    for (int k = 0; k < 20; k++) {
        int idx = base + k;
        int v = (idx < NN) ? cnt[idx] : 0;
        loc[k] = sum; sum += v;
    }
    s[t] = sum; __syncthreads();
    for (int o = 1; o < 1024; o <<= 1) {
        int a = (t >= o) ? s[t - o] : 0;
        __syncthreads();
        s[t] += a;
        __syncthreads();
    }
    int pre = s[t] - sum;
    #pragma unroll
    for (int k = 0; k < 20; k++) {
        int idx = base + k;
        if (idx < NN) { int e = pre + loc[k]; off[idx] = e; fill[idx] = e; }
    }
    if (t == 1023) off[NN] = s[1023];
}

__global__ void scatter_bucket_kernel(const int* __restrict__ bkarr,
        int* __restrict__ fill, int* __restrict__ blist) {
    int i = blockIdx.x * 256 + threadIdx.x;
    if (i < NN) {
        int b = min(max(bkarr[i], 0), NB - 1);
        int p = atomicAdd(&fill[b], 1);
        if (p >= 0 && p < NN) blist[p] = i;
    }
}

__global__ void edge_count_kernel(const int* __restrict__ ei, int* __restrict__ ecnt) {
    int e = blockIdx.x * 256 + threadIdx.x;
    if (e < NE) {
        int s = min(max(ei[e], 0), NN - 1);
        atomicAdd(&ecnt[s], 1);
    }
}

__global__ void edge_scatter_kernel(const int* __restrict__ ei,
        int* __restrict__ fill, int* __restrict__ adj) {
    int e = blockIdx.x * 256 + threadIdx.x;
    if (e < NE) {
        int s = min(max(ei[e], 0), NN - 1);
        int d = min(max(ei[NE + e], 0), NN - 1);
        int p = atomicAdd(&fill[s], 1);
        if (p >= 0 && p < NE) adj[p] = d;
    }
}

// ------- attention (one wave per src node) + fused h@W_out+b_out epilogue ------
__global__ __launch_bounds__(64) void attn_kernel(
    const float* __restrict__ Q, const float* __restrict__ K, const float* __restrict__ V,
    const float* __restrict__ lap,
    const float* __restrict__ spdb, const float* __restrict__ dse,
    const float* __restrict__ dde, const float* __restrict__ bndr,
    const int* __restrict__ deg,
    const int* __restrict__ bq, const int* __restrict__ bkarr,
    const int* __restrict__ boff, const int* __restrict__ blist,
    const int* __restrict__ eoff, const int* __restrict__ adj,
    const float* __restrict__ Wout, const float* __restrict__ bout,
    float* __restrict__ outH)
{
    __shared__ float qf[128];
    __shared__ float pef[16];
    __shared__ float bnd[32];
    __shared__ float red[64][33];
    __shared__ float hsm[128];
    const int i = blockIdx.x;
    const int lane = threadIdx.x;

    qf[lane]      = Q[(size_t)i * HID + lane];
    qf[lane + 64] = Q[(size_t)i * HID + 64 + lane];
    if (lane < 16) pef[lane] = lap[(size_t)i * LAPD + lane];
    if (lane < 32) bnd[lane] = bndr[lane];

    int b = min(max(bq[i], 0), NB - 1);
    int bs = boff[b], be = boff[b + 1];
    bs = min(max(bs, 0), NN); be = min(max(be, bs), NN);
    int es = eoff[i], ee = eoff[i + 1];
    es = min(max(es, 0), NE); ee = min(max(ee, es), NE);
    const int Lb = be - bs;
    const int Ltot = Lb + (ee - es);
    const int degi = min(max(deg[i], 0), MAXDEG + 1);
    __syncthreads();

    float dsrc[8];
    #pragma unroll
    for (int h = 0; h < 8; h++) dsrc[h] = dse[degi * 8 + h];

    float m8[8], l8[8], acc[128];
    #pragma unroll
    for (int h = 0; h < 8; h++) { m8[h] = NEGH; l8[h] = 0.0f; }
    #pragma unroll
    for (int cidx = 0; cidx < 128; cidx++) acc[cidx] = 0.0f;

    for (int t0 = 0; t0 < Ltot; t0 += 64) {
        const int t = t0 + lane;
        int j = 0; bool valid = false;
        if (t < Ltot) {
            if (t < Lb) {
                j = blist[bs + t];
                j = min(max(j, 0), NN - 1);
                valid = (j != i);
            } else {
                const int p = t - Lb;
                j = adj[es + p];
                j = min(max(j, 0), NN - 1);
                valid = (j == i) || (bkarr[j] != b);   // skip edges already in the LSH bucket
                if (valid) {
                    for (int q = 0; q < p; q++)        // drop duplicate edges (keep first)
                        if (adj[es + q] == j) { valid = false; break; }
                }
            }
        }
        float s8[8];
        if (valid) {
            const float4* K4 = (const float4*)(K + (size_t)j * HID);
            #pragma unroll
            for (int h = 0; h < 8; h++) {
                float4 k0 = K4[h * 4 + 0], k1 = K4[h * 4 + 1];
                float4 k2 = K4[h * 4 + 2], k3 = K4[h * 4 + 3];
                float dot = 0.0f;
                dot = fmaf(qf[h*16+ 0], k0.x, dot); dot = fmaf(qf[h*16+ 1], k0.y, dot);
                dot = fmaf(qf[h*16+ 2], k0.z, dot); dot = fmaf(qf[h*16+ 3], k0.w, dot);
                dot = fmaf(qf[h*16+ 4], k1.x, dot); dot = fmaf(qf[h*16+ 5], k1.y, dot);
                dot = fmaf(qf[h*16+ 6], k1.z, dot); dot = fmaf(qf[h*16+ 7], k1.w, dot);
                dot = fmaf(qf[h*16+ 8], k2.x, dot); dot = fmaf(qf[h*16+ 9], k2.y, dot);
                dot = fmaf(qf[h*16+10], k2.z, dot); dot = fmaf(qf[h*16+11], k2.w, dot);
                dot = fmaf(qf[h*16+12], k3.x, dot); dot = fmaf(qf[h*16+13], k3.y, dot);
                dot = fmaf(qf[h*16+14], k3.z, dot); dot = fmaf(qf[h*16+15], k3.w, dot);
                s8[h] = dot * 0.25f;   // /sqrt(16)
            }
            const float* lj = lap + (size_t)j * LAPD;
            float ss = 0.0f;
            #pragma unroll
            for (int d = 0; d < 16; d++) { float df = pef[d] - lj[d]; ss = fmaf(df, df, ss); }
            float dist = sqrtf(ss);
            int si = 0;
            #pragma unroll
            for (int kb = 0; kb < 32; kb++) si += (bnd[kb] < dist) ? 1 : 0;  // searchsorted left
            const int dj = min(max(deg[j], 0), MAXDEG + 1);
            #pragma unroll
            for (int h = 0; h < 8; h++)
                s8[h] += spdb[si * 8 + h] + dsrc[h] + dde[dj * 8 + h];
        } else {
            #pragma unroll
            for (int h = 0; h < 8; h++) s8[h] = NEGH;
        }

        float alpha8[8];
        #pragma unroll
        for (int h = 0; h < 8; h++) {
            float cm = s8[h];
            #pragma unroll
            for (int off = 1; off < 64; off <<= 1)
                cm = fmaxf(cm, __shfl_xor(cm, off, 64));
            const float mn = fmaxf(m8[h], cm);
            // no inf anywhere: if m8==mn==NEGH -> exp(0)=1 (empty-so-far chunk);
            // if m8==NEGH, mn real -> exp(-1e30) underflows to 0.
            alpha8[h] = __expf(m8[h] - mn);
            const float p = valid ? __expf(s8[h] - mn) : 0.0f;
            l8[h] = l8[h] * alpha8[h] + p;
            m8[h] = mn;
            s8[h] = p;   // reuse as weight
        }

        const float4* V4 = (const float4*)(V + (size_t)j * HID);
        #pragma unroll
        for (int h = 0; h < 8; h++) {
            float4 v0, v1, v2, v3;
            if (valid) {
                v0 = V4[h * 4 + 0]; v1 = V4[h * 4 + 1];
                v2 = V4[h * 4 + 2]; v3 = V4[h * 4 + 3];
            } else {
                v0 = v1 = v2 = v3 = make_float4(0.f, 0.f, 0.f, 0.f);
            }
            const float p = s8[h], al = alpha8[h];
            float* a = &acc[h * 16];
            a[ 0] = fmaf(p, v0.x, a[ 0] * al); a[ 1] = fmaf(p, v0.y, a[ 1] * al);
            a[ 2] = fmaf(p, v0.z, a[ 2] * al); a[ 3] = fmaf(p, v0.w, a[ 3] * al);
            a[ 4] = fmaf(p, v1.x, a[ 4] * al); a[ 5] = fmaf(p, v1.y, a[ 5] * al);
            a[ 6] = fmaf(p, v1.z, a[ 6] * al); a[ 7] = fmaf(p, v1.w, a[ 7] * al);
            a[ 8] = fmaf(p, v2.x, a[ 8] * al); a[ 9] = fmaf(p, v2.y, a[ 9] * al);
            a[10] = fmaf(p, v2.z, a[10] * al); a[11] = fmaf(p, v2.w, a[11] * al);
            a[12] = fmaf(p, v3.x, a[12] * al); a[13] = fmaf(p, v3.y, a[13] * al);
            a[14] = fmaf(p, v3.z, a[14] * al); a[15] = fmaf(p, v3.w, a[15] * al);
        }
    }

    #pragma unroll
    for (int h = 0; h < 8; h++) {
        float v = l8[h];
        #pragma unroll
        for (int off = 1; off < 64; off <<= 1) v += __shfl_xor(v, off, 64);
        l8[h] = 1.0f / (v + 1e-16f);
    }

    const int cc = lane & 31, half = lane >> 5;
    #pragma unroll
    for (int g = 0; g < 4; g++) {
        __syncthreads();
        #pragma unroll
        for (int k = 0; k < 32; k++) red[lane][k] = acc[g * 32 + k];
        __syncthreads();
        float v = 0.0f;
        #pragma unroll
        for (int jj = 0; jj < 32; jj++) v += red[half * 32 + jj][cc];
        v += __shfl_xor(v, 32, 64);
        if (half == 0) {
            const int cidx = g * 32 + cc;
            hsm[cidx] = v * l8[cidx >> 4];
        }
    }
    __syncthreads();

    // fused epilogue: out[i, c] = b_out[c] + sum_k h[k] * W_out[k][c]
    float o0 = bout[lane];
    float o1 = bout[lane + 64];
    for (int k = 0; k < HID; k++) {
        const float hk = hsm[k];
        o0 = fmaf(hk, Wout[k * HID + lane], o0);
        o1 = fmaf(hk, Wout[k * HID + 64 + lane], o1);
    }
    outH[(size_t)i * HID + lane]      = o0;
    outH[(size_t)i * HID + 64 + lane] = o1;
}

// ---------------- launch --------------------------------------------------------
extern "C" void kernel_launch(void* const* d_in, const int* in_sizes, int n_in,
                              void* d_out, int out_size, void* d_ws, size_t ws_size,
                              hipStream_t stream) {
    const float* Q    = (const float*)d_in[0];
    const float* Kx   = (const float*)d_in[1];
    const float* Vx   = (const float*)d_in[2];
    const float* lap  = (const float*)d_in[3];
    const float* Wq1  = (const float*)d_in[4];
    const float* bq1  = (const float*)d_in[5];
    const float* Wq2  = (const float*)d_in[6];
    const float* bq2  = (const float*)d_in[7];
    const float* Wk1  = (const float*)d_in[8];
    const float* bk1  = (const float*)d_in[9];
    const float* Wk2  = (const float*)d_in[10];
    const float* bk2  = (const float*)d_in[11];
    const float* spdb = (const float*)d_in[12];
    const float* dse  = (const float*)d_in[13];
    const float* dde  = (const float*)d_in[14];
    const float* Wout = (const float*)d_in[15];
    const float* bout = (const float*)d_in[16];
    const float* bndr = (const float*)d_in[17];
    const int*   ei   = (const int*)d_in[18];
    const int*   deg  = (const int*)d_in[19];

    float* out   = (float*)d_out;
    float* outH  = out;
    float* outLq = out + (size_t)NN * HID;
    float* outLk = outLq + (size_t)NN * NB;

    // workspace: ~1.69 MB total (keep small — ws_size is unknown)
    int* wsp = (int*)d_ws;
    size_t o = 0;
    auto carve = [&](size_t n_ints) -> int* {
        int* p = wsp + o; o += n_ints; return p;
    };
    int* bcnt  = carve(NB);
    int* boff  = carve(NB + 1);
    int* bfill = carve(NB);
    int* blist = carve(NN);
    int* bqv   = carve(NN);
    int* bkv   = carve(NN);
    int* ecnt  = carve(NN);
    int* eoff  = carve(NN + 1);
    int* efill = carve(NN);
    int* adj   = carve(NE);

    zero_kernel<<<(NB + 255) / 256, 256, 0, stream>>>(bcnt, NB);
    zero_kernel<<<(NN + 255) / 256, 256, 0, stream>>>(ecnt, NN);

    mlp_kernel<<<NN / 16, 256, 0, stream>>>(Q,  lap, Wq1, bq1, Wq2, bq2, outLq, bqv);
    mlp_kernel<<<NN / 16, 256, 0, stream>>>(Kx, lap, Wk1, bk1, Wk2, bk2, outLk, bkv);

    hist_kernel<<<(NN + 255) / 256, 256, 0, stream>>>(bkv, bcnt);
    scan_bucket_kernel<<<1, 1024, 0, stream>>>(bcnt, boff, bfill);
    scatter_bucket_kernel<<<(NN + 255) / 256, 256, 0, stream>>>(bkv, bfill, blist);

    edge_count_kernel<<<(NE + 255) / 256, 256, 0, stream>>>(ei, ecnt);
    scan_edge_kernel<<<1, 1024, 0, stream>>>(ecnt, eoff, efill);
    edge_scatter_kernel<<<(NE + 255) / 256, 256, 0, stream>>>(ei, efill, adj);

    attn_kernel<<<NN, 64, 0, stream>>>(Q, Kx, Vx, lap, spdb, dse, dde, bndr, deg,
                                       bqv, bkv, boff, blist, eoff, adj,
                                       Wout, bout, outH);
}